// Round 4
// baseline (1871.647 us; speedup 1.0000x reference)
//
#include <hip/hip_runtime.h>
#include <math.h>

#define NT 64
#define KN 48
#define TOBS 30
#define NPRED 15
#define EMB 64
#define NODE 128
#define EDGE 256
#define ATTD 64
#define CNN 512
#define GNN 1024
#define GTT 512
#define KKA 320
#define TMAX 44

typedef _Float16 f16;
typedef f16 f16x8 __attribute__((ext_vector_type(8)));
typedef float f32x4 __attribute__((ext_vector_type(4)));

__device__ __forceinline__ float sigm(float x) {
  return 1.f / (1.f + __expf(-x));
}
__device__ __forceinline__ float tanh_f(float x) {
  float xx = fminf(fmaxf(x, -20.f), 20.f);
  float e = __expf(-2.f * xx);
  return (1.f - e) / (1.f + e);
}

// ---------------- prep: swizzle weights to MFMA-fragment-major f16, combine biases, precompute gates ----------------
// Wn_sw element index = ((kk*64 + g*16 + q)*64 + lane)*8 + j
//   value = Wn[col][k], col = g*256 + q*16 + (lane&15), k = kk*32 + (lane>>4)*8 + j
// Wt_sw element index = (c8*512 + col)*8 + j ; value = Wt[col][c8*8+j]
__global__ __launch_bounds__(256) void prep_kernel(
    const float* __restrict__ Wih_n, const float* __restrict__ Whh_n,
    const float* __restrict__ bih_n, const float* __restrict__ bhh_n,
    const float* __restrict__ Wih_t, const float* __restrict__ Whh_t,
    const float* __restrict__ bih_t, const float* __restrict__ bhh_t,
    const int* __restrict__ t_hist, const int* __restrict__ n_hist,
    f16* __restrict__ Wn, f16* __restrict__ Wt,
    float* __restrict__ bias_n, float* __restrict__ bias_t,
    int* __restrict__ gt_arr, int* __restrict__ gn_arr, float* __restrict__ cn_arr)
{
  const int gid = blockIdx.x * 256 + threadIdx.x;
  const int nthr = gridDim.x * 256;

  for (int idx = gid; idx < GNN * KKA; idx += nthr) {
    const int j = idx & 7;
    const int lane = (idx >> 3) & 63;
    const int fidx = idx >> 9;          // kk*64 + g*16 + q
    const int q = fidx & 15;
    const int g = (fidx >> 4) & 3;
    const int kk = fidx >> 6;
    const int col = g * 256 + q * 16 + (lane & 15);
    const int k = kk * 32 + (lane >> 4) * 8 + j;
    const float v = (k < EMB) ? Wih_n[col * EMB + k] : Whh_n[col * EDGE + (k - EMB)];
    Wn[idx] = (f16)v;
  }
  for (int idx = gid; idx < GTT * 192; idx += nthr) {
    const int j = idx & 7;
    const int col = (idx >> 3) & 511;
    const int c8 = idx >> 12;
    const int k = c8 * 8 + j;
    const float v = (k < EMB) ? Wih_t[col * EMB + k] : Whh_t[col * NODE + (k - EMB)];
    Wt[idx] = (f16)v;
  }
  for (int idx = gid; idx < GNN; idx += nthr) bias_n[idx] = bih_n[idx] + bhh_n[idx];
  for (int idx = gid; idx < GTT; idx += nthr) bias_t[idx] = bih_t[idx] + bhh_t[idx];

  if (blockIdx.x == 0 && threadIdx.x < 352) {
    const int t = (threadIdx.x >> 3) + 1;   // 1..44
    const int part = threadIdx.x & 7;
    int any_t = 0, cnt = 0;
    if (t < TOBS) {
      const int thr = TOBS - t;
      for (int nn = part; nn < NT; nn += 8) any_t |= (t_hist[nn] > thr) ? 1 : 0;
      for (int m = part; m < NT * KN; m += 8) cnt += (n_hist[m] > thr) ? 1 : 0;
    } else { any_t = (part == 0); cnt = (part == 0) ? NT * KN : 0; }
    #pragma unroll
    for (int off = 1; off < 8; off <<= 1) {
      any_t |= __shfl_xor(any_t, off);
      cnt   += __shfl_xor(cnt, off);
    }
    if (part == 0) {
      gt_arr[t] = any_t;
      gn_arr[t] = (any_t && cnt > 0) ? 1 : 0;
      cn_arr[t] = (float)cnt;
    }
  }
}

// ---------------- main: one 1024-thread workgroup per target, pinned 4 waves/EU (VGPR cap 128) ----------------
__global__ __launch_bounds__(1024)
__attribute__((amdgpu_waves_per_eu(4, 4)))
void model_kernel(
    const float* __restrict__ img, const float* __restrict__ tabs,
    const float* __restrict__ trel, const float* __restrict__ tstep,
    const float* __restrict__ nabs_g, const float* __restrict__ nstep_g,
    const int* __restrict__ thist_g, const int* __restrict__ nhist_g,
    const float* __restrict__ W_disp, const float* __restrict__ b_disp,
    const float* __restrict__ W_att_t, const float* __restrict__ b_att_t,
    const float* __restrict__ W_att_n, const float* __restrict__ b_att_n,
    const float* __restrict__ W_pred, const float* __restrict__ b_pred,
    const f16* __restrict__ Wn, const f16* __restrict__ Wt,
    const float* __restrict__ bias_n, const float* __restrict__ bias_t,
    const int* __restrict__ gt_arr, const int* __restrict__ gn_arr,
    const float* __restrict__ cn_arr,
    float* __restrict__ out)
{
  __shared__ f16 Ax[KN][EMB + 8];
  __shared__ f16 Ah[KN][EDGE + 8];
  __shared__ float s_tht[NODE], s_tct[NODE];
  __shared__ float s_Ht[EDGE];
  __shared__ float s_xt[EMB];
  __shared__ float s_g[GTT];
  __shared__ float s_bt[GTT];
  __shared__ float s_at[ATTD];
  __shared__ float s_sc[KN], s_w[KN];
  __shared__ float s_scal[8];        // [0..1]=cabs [2..3]=crel [4..5]=cstep [6..7]=pred_out
  __shared__ float s_pimg[2];
  __shared__ int   s_nh[KN];
  __shared__ float s_wp[2][384];     // [0:128)=tht part, [128:384)=Ht part
  __shared__ float s_wan0[ATTD], s_wan1[ATTD], s_ban[ATTD];
  __shared__ float s_wat0[ATTD], s_wat1[ATTD], s_bat[ATTD];
  __shared__ float s_wd0[EMB], s_wd1[EMB], s_bd[EMB];

  const int tid  = threadIdx.x;
  const int n    = blockIdx.x;
  const int w    = tid >> 6;     // wave 0..15
  const int lane = tid & 63;
  const int cl   = lane & 15;
  const int kq   = lane >> 4;    // 0..3
  const int koff = kq * 8;
  const int q    = w;            // col group 0..15

  // ---- one-time init / LDS caching ----
  for (int i = tid; i < KN * EDGE; i += 1024) Ah[i >> 8][i & 255] = (f16)0.f;
  for (int i = tid; i < NODE; i += 1024) { s_tht[i] = 0.f; s_tct[i] = 0.f; }
  for (int i = tid; i < EDGE; i += 1024) s_Ht[i] = 0.f;
  for (int i = tid; i < GTT; i += 1024) s_bt[i] = bias_t[i];
  for (int i = tid; i < 768; i += 1024) {
    const int ww = i / 384, j = i - ww * 384;
    s_wp[ww][j] = (j < 128) ? W_pred[ww * 896 + j] : W_pred[ww * 896 + 640 + (j - 128)];
  }
  if (tid < KN) s_nh[tid] = nhist_g[n * KN + tid];
  if (tid < 8) s_scal[tid] = 0.f;
  if (tid >= 64 && tid < 128) {
    const int a = tid - 64;
    s_wan0[a] = W_att_n[a * 2]; s_wan1[a] = W_att_n[a * 2 + 1]; s_ban[a] = b_att_n[a];
  }
  if (tid >= 128 && tid < 192) {
    const int a = tid - 128;
    s_wat0[a] = W_att_t[a * 2]; s_wat1[a] = W_att_t[a * 2 + 1]; s_bat[a] = b_att_t[a];
  }
  if (tid >= 192 && tid < 256) {
    const int e = tid - 192;
    s_wd0[e] = W_disp[e * 2]; s_wd1[e] = W_disp[e * 2 + 1]; s_bd[e] = b_disp[e];
  }
  const int thist = thist_g[n];

  // img @ W_pred (constant part) + b_pred
  if (w < 2) {
    float s = 0.f;
    for (int j = lane; j < CNN; j += 64) s += img[n * CNN + j] * W_pred[w * 896 + 128 + j];
    for (int off = 32; off; off >>= 1) s += __shfl_down(s, off);
    if (lane == 0) s_pimg[w] = s + b_pred[w];
  }

  // persistent per-lane nearby cell state: rows rt*16+kq*4+jj, hidden dim e=q*16+cl
  float creg[3][4];
  #pragma unroll
  for (int b = 0; b < 3; ++b)
    #pragma unroll
    for (int c = 0; c < 4; ++c) creg[b][c] = 0.f;

  float bias_q[4];
  #pragma unroll
  for (int g = 0; g < 4; ++g) bias_q[g] = bias_n[g * 256 + q * 16 + cl];

  const f16* wbase = Wn + ((size_t)(q * 64 + lane)) * 8;   // + kk*32768 + g*8192
  const int e_mine = q * 16 + cl;

  __syncthreads();

  for (int t = 1; t <= TMAX; ++t) {
    const bool is_obs = (t < TOBS);
    const int tc = is_obs ? t : (TOBS - 1);
    const int gate_t = gt_arr[t];
    const int gate_n = gn_arr[t];
    const float currN = cn_arr[t];

    // ---- P0: pred_out + scalar state update ----
    if (!is_obs) {
      if (w < 2) {
        float s = 0.f;
        for (int j = lane; j < NODE; j += 64) s += s_tht[j] * s_wp[w][j];
        for (int j = lane; j < EDGE; j += 64) s += s_Ht[j] * s_wp[w][128 + j];
        for (int off = 32; off; off >>= 1) s += __shfl_down(s, off);
        if (lane == 0) {
          const float p = s + s_pimg[w];
          const float cabs = s_scal[w] + p;
          const float crel = s_scal[2 + w] + p;
          s_scal[w] = cabs; s_scal[2 + w] = crel; s_scal[4 + w] = p; s_scal[6 + w] = p;
          out[(n * NPRED + (t - TOBS)) * 2 + w] = crel;
        }
      }
    } else if (tid < 2) {
      const int d = tid;
      s_scal[d]     = tabs[(n * TOBS + tc) * 2 + d];
      s_scal[2 + d] = trel[(n * TOBS + tc) * 2 + d];
      s_scal[4 + d] = tstep[(n * TOBS + tc) * 2 + d];
    }
    __syncthreads();  // A

    // ---- P1: stage Ax (frozen after t=30), s_xt, s_at ----
    if (t <= TOBS) {
      for (int i = tid; i < KN * EMB; i += 1024) {
        const int k = i >> 6, e = i & 63;
        const float s0 = nstep_g[((n * KN + k) * TOBS + tc) * 2 + 0];
        const float s1 = nstep_g[((n * KN + k) * TOBS + tc) * 2 + 1];
        Ax[k][e] = (f16)(s0 * s_wd0[e] + s1 * s_wd1[e] + s_bd[e]);
      }
    }
    if (tid >= 960) {
      const int e = tid - 960;
      s_xt[e] = s_scal[4] * s_wd0[e] + s_scal[5] * s_wd1[e] + s_bd[e];
    }
    if (tid >= 896 && tid < 960) {
      const int a = tid - 896;
      s_at[a] = s_scal[2] * s_wat0[a] + s_scal[3] * s_wat1[a] + s_bat[a];
    }
    __syncthreads();  // B

    // ---- P2: nearby LSTM gates via MFMA (coalesced fragment-major weight loads) ----
    if (gate_n) {
      f32x4 acc[3][4];
      #pragma unroll
      for (int rt = 0; rt < 3; ++rt)
        #pragma unroll
        for (int g = 0; g < 4; ++g) acc[rt][g] = (f32x4){0.f, 0.f, 0.f, 0.f};

      #pragma unroll
      for (int kk = 0; kk < 10; ++kk) {
        f16x8 bf[4];
        #pragma unroll
        for (int g = 0; g < 4; ++g)
          bf[g] = *(const f16x8*)(wbase + kk * 32768 + g * 8192);
        f16x8 af[3];
        #pragma unroll
        for (int rt = 0; rt < 3; ++rt) {
          const int row = rt * 16 + cl;
          const f16* ap = (kk < 2) ? &Ax[row][kk * 32 + koff]
                                   : &Ah[row][(kk - 2) * 32 + koff];
          af[rt] = *(const f16x8*)ap;
        }
        #pragma unroll
        for (int g = 0; g < 4; ++g)
          #pragma unroll
          for (int rt = 0; rt < 3; ++rt)
            acc[rt][g] = __builtin_amdgcn_mfma_f32_16x16x32_f16(af[rt], bf[g], acc[rt][g], 0, 0, 0);
      }
      __syncthreads();  // C: all Ah reads done before rewrite

      // ---- P3: activations, update h (Ah) and c (regs) ----
      #pragma unroll
      for (int rt = 0; rt < 3; ++rt) {
        #pragma unroll
        for (int jj = 0; jj < 4; ++jj) {
          const int row = rt * 16 + kq * 4 + jj;
          const bool nm = is_obs ? (s_nh[row] > (TOBS - t)) : true;
          if (nm) {
            const float iv = acc[rt][0][jj] + bias_q[0];
            const float fv = acc[rt][1][jj] + bias_q[1];
            const float gv = acc[rt][2][jj] + bias_q[2];
            const float ov = acc[rt][3][jj] + bias_q[3];
            const float c2 = sigm(fv) * creg[rt][jj] + sigm(iv) * tanh_f(gv);
            creg[rt][jj] = c2;
            Ah[row][e_mine] = (f16)(sigm(ov) * tanh_f(c2));
          }
        }
      }
      __syncthreads();  // D
    }

    // ---- P4: target gate dot (tid<512) + attention scores (tid 512..559) ----
    const bool tmask = is_obs ? (thist > (TOBS - t)) : true;
    const bool do_t = gate_t && tmask;
    if (do_t && tid < GTT) {
      float g = s_bt[tid];
      const f16x8* wp = (const f16x8*)(Wt + tid * 8);
      #pragma unroll
      for (int c8 = 0; c8 < 8; ++c8) {
        const f16x8 wv = wp[c8 * 512];
        #pragma unroll
        for (int j = 0; j < 8; ++j) g += (float)wv[j] * s_xt[c8 * 8 + j];
      }
      #pragma unroll
      for (int c8 = 8; c8 < 24; ++c8) {
        const f16x8 wv = wp[c8 * 512];
        #pragma unroll
        for (int j = 0; j < 8; ++j) g += (float)wv[j] * s_tht[(c8 - 8) * 8 + j];
      }
      s_g[tid] = g;
    }
    if (gate_n && tid >= GTT && tid < GTT + KN) {
      const int k = tid - GTT;
      const float a0 = nabs_g[((n * KN + k) * TOBS + tc) * 2 + 0] - s_scal[0];
      const float a1 = nabs_g[((n * KN + k) * TOBS + tc) * 2 + 1] - s_scal[1];
      const bool nm = is_obs ? (s_nh[k] > (TOBS - t)) : true;
      float sc = 0.f;
      for (int a = 0; a < ATTD; ++a)
        sc += (a0 * s_wan0[a] + a1 * s_wan1[a] + s_ban[a]) * s_at[a];
      sc *= currN * 0.125f;
      s_sc[k] = nm ? sc : 0.f;
      s_w[k]  = nm ? 1.f : 0.f;
    }
    __syncthreads();  // E

    // ---- P5: target cell update (tid<128) + softmax (wave 2) ----
    if (do_t && tid < NODE) {
      const float iv = s_g[tid], fv = s_g[NODE + tid];
      const float gv = s_g[2 * NODE + tid], ov = s_g[3 * NODE + tid];
      const float c2 = sigm(fv) * s_tct[tid] + sigm(iv) * tanh_f(gv);
      s_tct[tid] = c2;
      s_tht[tid] = sigm(ov) * tanh_f(c2);
    }
    if (gate_n && w == 2) {
      const bool act = lane < KN;
      const float sc = act ? s_sc[lane] : -1.0e30f;
      const float mf = act ? s_w[lane] : 0.f;
      float mx = sc;
      #pragma unroll
      for (int off = 32; off; off >>= 1) mx = fmaxf(mx, __shfl_xor(mx, off));
      float num = __expf(sc - mx) * mf;
      float sum = num;
      #pragma unroll
      for (int off = 32; off; off >>= 1) sum += __shfl_xor(sum, off);
      if (act) s_w[lane] = num / (sum + 1e-6f);
    }
    __syncthreads();  // F

    // ---- P6: Ht ----
    if (gate_n && tid < EDGE) {
      float h = 0.f;
      for (int k = 0; k < KN; ++k) h += (float)Ah[k][tid] * s_w[k];
      s_Ht[tid] = h;
    }
    __syncthreads();  // G
  }
}

extern "C" void kernel_launch(void* const* d_in, const int* in_sizes, int n_in,
                              void* d_out, int out_size, void* d_ws, size_t ws_size,
                              hipStream_t stream) {
  const float* img    = (const float*)d_in[0];
  const float* tabs   = (const float*)d_in[1];
  const float* trel   = (const float*)d_in[2];
  const float* tstep  = (const float*)d_in[3];
  const float* nabs   = (const float*)d_in[4];
  const float* nstep  = (const float*)d_in[6];
  const int*   thist  = (const int*)d_in[7];
  const int*   nhist  = (const int*)d_in[8];
  const float* W_disp = (const float*)d_in[9];
  const float* b_disp = (const float*)d_in[10];
  const float* Wih_t  = (const float*)d_in[11];
  const float* Whh_t  = (const float*)d_in[12];
  const float* bih_t  = (const float*)d_in[13];
  const float* bhh_t  = (const float*)d_in[14];
  const float* Wih_n  = (const float*)d_in[15];
  const float* Whh_n  = (const float*)d_in[16];
  const float* bih_n  = (const float*)d_in[17];
  const float* bhh_n  = (const float*)d_in[18];
  const float* W_att_t = (const float*)d_in[19];
  const float* b_att_t = (const float*)d_in[20];
  const float* W_att_n = (const float*)d_in[21];
  const float* b_att_n = (const float*)d_in[22];
  const float* W_pred  = (const float*)d_in[23];
  const float* b_pred  = (const float*)d_in[24];

  char* ws = (char*)d_ws;
  f16*   Wn     = (f16*)(ws);             // 655360 B
  f16*   Wt     = (f16*)(ws + 655360);    // 196608 B
  float* bias_n = (float*)(ws + 851968);  // 4096 B
  float* bias_t = (float*)(ws + 856064);  // 2048 B
  int*   gt_arr = (int*)(ws + 858112);
  int*   gn_arr = (int*)(ws + 858304);
  float* cn_arr = (float*)(ws + 858496);

  prep_kernel<<<64, 256, 0, stream>>>(Wih_n, Whh_n, bih_n, bhh_n, Wih_t, Whh_t,
                                      bih_t, bhh_t, thist, nhist, Wn, Wt,
                                      bias_n, bias_t, gt_arr, gn_arr, cn_arr);
  model_kernel<<<NT, 1024, 0, stream>>>(img, tabs, trel, tstep, nabs, nstep,
                                        thist, nhist, W_disp, b_disp,
                                        W_att_t, b_att_t, W_att_n, b_att_n,
                                        W_pred, b_pred,
                                        Wn, Wt, bias_n, bias_t,
                                        gt_arr, gn_arr, cn_arr,
                                        (float*)d_out);
}

// Round 5
// 1287.439 us; speedup vs baseline: 1.4538x; 1.4538x over previous
//
#include <hip/hip_runtime.h>
#include <math.h>

#define NT 64
#define KN 48
#define TOBS 30
#define NPRED 15
#define EMB 64
#define NODE 128
#define EDGE 256
#define ATTD 64
#define CNN 512
#define GNN 1024
#define GTT 512
#define KKA 320
#define TMAX 44

typedef _Float16 f16;
typedef f16 f16x8 __attribute__((ext_vector_type(8)));
typedef float f32x4 __attribute__((ext_vector_type(4)));

__device__ __forceinline__ float sigm(float x) {
  return 1.f / (1.f + __expf(-x));
}
__device__ __forceinline__ float tanh_f(float x) {
  float xx = fminf(fmaxf(x, -20.f), 20.f);
  float e = __expf(-2.f * xx);
  return (1.f - e) / (1.f + e);
}

// ---------------- prep: swizzle weights to MFMA-fragment-major f16 ----------------
// Wn_sw flat idx = kk*32768 + p*16384 + w*2048 + g*512 + lane*8 + j
//   value = Wn_rowmajor[col][k], col = g*256 + p*128 + w*16 + (lane&15),
//                                k   = kk*32 + (lane>>4)*8 + j
// -> for wave w, pass p, step (kk,g): lanes read 512 contiguous f16 (1 KB), fully coalesced.
// Wt_sw flat idx = (c8*512 + col)*8 + j ; value = Wt_rowmajor[col][c8*8+j]
__global__ __launch_bounds__(256) void prep_kernel(
    const float* __restrict__ Wih_n, const float* __restrict__ Whh_n,
    const float* __restrict__ bih_n, const float* __restrict__ bhh_n,
    const float* __restrict__ Wih_t, const float* __restrict__ Whh_t,
    const float* __restrict__ bih_t, const float* __restrict__ bhh_t,
    const int* __restrict__ t_hist, const int* __restrict__ n_hist,
    f16* __restrict__ Wn, f16* __restrict__ Wt,
    float* __restrict__ bias_n, float* __restrict__ bias_t,
    int* __restrict__ gt_arr, int* __restrict__ gn_arr, float* __restrict__ cn_arr)
{
  const int gid = blockIdx.x * 256 + threadIdx.x;
  const int nthr = gridDim.x * 256;

  for (int idx = gid; idx < GNN * KKA; idx += nthr) {
    const int j    = idx & 7;
    const int lane = (idx >> 3) & 63;
    const int g    = (idx >> 9) & 3;
    const int w    = (idx >> 11) & 7;
    const int p    = (idx >> 14) & 1;
    const int kk   = idx >> 15;
    const int col = g * 256 + p * 128 + w * 16 + (lane & 15);
    const int k   = kk * 32 + (lane >> 4) * 8 + j;
    const float v = (k < EMB) ? Wih_n[col * EMB + k] : Whh_n[col * EDGE + (k - EMB)];
    Wn[idx] = (f16)v;
  }
  for (int idx = gid; idx < GTT * 192; idx += nthr) {
    const int j = idx & 7;
    const int col = (idx >> 3) & 511;
    const int c8 = idx >> 12;
    const int k = c8 * 8 + j;
    const float v = (k < EMB) ? Wih_t[col * EMB + k] : Whh_t[col * NODE + (k - EMB)];
    Wt[idx] = (f16)v;
  }
  for (int idx = gid; idx < GNN; idx += nthr) bias_n[idx] = bih_n[idx] + bhh_n[idx];
  for (int idx = gid; idx < GTT; idx += nthr) bias_t[idx] = bih_t[idx] + bhh_t[idx];

  if (blockIdx.x == 0 && threadIdx.x < 352) {
    const int t = (threadIdx.x >> 3) + 1;   // 1..44
    const int part = threadIdx.x & 7;
    int any_t = 0, cnt = 0;
    if (t < TOBS) {
      const int thr = TOBS - t;
      for (int nn = part; nn < NT; nn += 8) any_t |= (t_hist[nn] > thr) ? 1 : 0;
      for (int m = part; m < NT * KN; m += 8) cnt += (n_hist[m] > thr) ? 1 : 0;
    } else { any_t = (part == 0); cnt = (part == 0) ? NT * KN : 0; }
    #pragma unroll
    for (int off = 1; off < 8; off <<= 1) {
      any_t |= __shfl_xor(any_t, off);
      cnt   += __shfl_xor(cnt, off);
    }
    if (part == 0) {
      gt_arr[t] = any_t;
      gn_arr[t] = (any_t && cnt > 0) ? 1 : 0;
      cn_arr[t] = (float)cnt;
    }
  }
}

// ---------------- main: one 512-thread workgroup per target ----------------
// Per wave w (0..7), pass p (0..1): computes gates for hidden dims e = p*128 + w*16 + [0,16)
// (all 4 gates), all 48 rows. acc = 3x4 f32x4 = 48 VGPRs per pass. Ah double-buffered:
// both passes read Ah[prv], write Ah[nxt]; no intra-P2 barrier needed.
__global__ __launch_bounds__(512, 2) void model_kernel(
    const float* __restrict__ img, const float* __restrict__ tabs,
    const float* __restrict__ trel, const float* __restrict__ tstep,
    const float* __restrict__ nabs_g, const float* __restrict__ nstep_g,
    const int* __restrict__ thist_g, const int* __restrict__ nhist_g,
    const float* __restrict__ W_disp, const float* __restrict__ b_disp,
    const float* __restrict__ W_att_t, const float* __restrict__ b_att_t,
    const float* __restrict__ W_att_n, const float* __restrict__ b_att_n,
    const float* __restrict__ W_pred, const float* __restrict__ b_pred,
    const f16* __restrict__ Wn, const f16* __restrict__ Wt,
    const float* __restrict__ bias_n, const float* __restrict__ bias_t,
    const int* __restrict__ gt_arr, const int* __restrict__ gn_arr,
    const float* __restrict__ cn_arr,
    float* __restrict__ out)
{
  __shared__ f16 Ax[KN][EMB + 8];
  __shared__ f16 Ah[2][KN][EDGE + 8];
  __shared__ float s_tht[NODE], s_tct[NODE];
  __shared__ float s_Ht[EDGE];
  __shared__ float s_xt[EMB];
  __shared__ float s_g[GTT];
  __shared__ float s_bt[GTT];
  __shared__ float s_at[ATTD];
  __shared__ float s_sc[KN], s_w[KN];
  __shared__ float s_scal[8];        // [0..1]=cabs [2..3]=crel [4..5]=cstep
  __shared__ float s_pimg[2];
  __shared__ int   s_nh[KN];
  __shared__ float s_wp[2][384];     // [0:128)=tht part, [128:384)=Ht part
  __shared__ float s_wan0[ATTD], s_wan1[ATTD], s_ban[ATTD];
  __shared__ float s_wat0[ATTD], s_wat1[ATTD], s_bat[ATTD];
  __shared__ float s_wd0[EMB], s_wd1[EMB], s_bd[EMB];

  const int tid  = threadIdx.x;
  const int n    = blockIdx.x;
  const int w    = tid >> 6;     // wave 0..7
  const int lane = tid & 63;
  const int cl   = lane & 15;
  const int kq   = lane >> 4;    // 0..3
  const int koff = kq * 8;

  // ---- one-time init / LDS caching ----
  for (int i = tid; i < 2 * KN * (EDGE + 8); i += 512) ((f16*)Ah)[i] = (f16)0.f;
  for (int i = tid; i < NODE; i += 512) { s_tht[i] = 0.f; s_tct[i] = 0.f; }
  for (int i = tid; i < EDGE; i += 512) s_Ht[i] = 0.f;
  for (int i = tid; i < GTT; i += 512) s_bt[i] = bias_t[i];
  for (int i = tid; i < 768; i += 512) {
    const int ww = i / 384, j = i - ww * 384;
    s_wp[ww][j] = (j < 128) ? W_pred[ww * 896 + j] : W_pred[ww * 896 + 640 + (j - 128)];
  }
  if (tid < KN) s_nh[tid] = nhist_g[n * KN + tid];
  if (tid < 8) s_scal[tid] = 0.f;
  if (tid >= 64 && tid < 128) {
    const int a = tid - 64;
    s_wan0[a] = W_att_n[a * 2]; s_wan1[a] = W_att_n[a * 2 + 1]; s_ban[a] = b_att_n[a];
  }
  if (tid >= 128 && tid < 192) {
    const int a = tid - 128;
    s_wat0[a] = W_att_t[a * 2]; s_wat1[a] = W_att_t[a * 2 + 1]; s_bat[a] = b_att_t[a];
  }
  if (tid >= 192 && tid < 256) {
    const int e = tid - 192;
    s_wd0[e] = W_disp[e * 2]; s_wd1[e] = W_disp[e * 2 + 1]; s_bd[e] = b_disp[e];
  }
  const int thist = thist_g[n];

  // img @ W_pred (constant part) + b_pred
  if (w < 2) {
    float s = 0.f;
    for (int j = lane; j < CNN; j += 64) s += img[n * CNN + j] * W_pred[w * 896 + 128 + j];
    for (int off = 32; off; off >>= 1) s += __shfl_down(s, off);
    if (lane == 0) s_pimg[w] = s + b_pred[w];
  }

  // persistent per-lane nearby cell state: pass p, rows rt*16+kq*4+jj, e = p*128+w*16+cl
  float creg[2][3][4];
  #pragma unroll
  for (int a = 0; a < 2; ++a)
    #pragma unroll
    for (int b = 0; b < 3; ++b)
      #pragma unroll
      for (int c = 0; c < 4; ++c) creg[a][b][c] = 0.f;

  float bias_q[2][4];
  #pragma unroll
  for (int p = 0; p < 2; ++p)
    #pragma unroll
    for (int g = 0; g < 4; ++g)
      bias_q[p][g] = bias_n[g * 256 + p * 128 + w * 16 + cl];

  const f16* wb0 = Wn + (size_t)(0 * 8 + w) * 2048 + lane * 8;
  const f16* wb1 = Wn + (size_t)(1 * 8 + w) * 2048 + lane * 8;
  int prv = 0;

  __syncthreads();

  for (int t = 1; t <= TMAX; ++t) {
    const bool is_obs = (t < TOBS);
    const int tc = is_obs ? t : (TOBS - 1);
    const int gate_t = gt_arr[t];
    const int gate_n = gn_arr[t];
    const float currN = cn_arr[t];

    // ---- P0: pred_out + scalar state update ----
    if (!is_obs) {
      if (w < 2) {
        float s = 0.f;
        for (int j = lane; j < NODE; j += 64) s += s_tht[j] * s_wp[w][j];
        for (int j = lane; j < EDGE; j += 64) s += s_Ht[j] * s_wp[w][128 + j];
        for (int off = 32; off; off >>= 1) s += __shfl_down(s, off);
        if (lane == 0) {
          const float p = s + s_pimg[w];
          const float cabs = s_scal[w] + p;
          const float crel = s_scal[2 + w] + p;
          s_scal[w] = cabs; s_scal[2 + w] = crel; s_scal[4 + w] = p;
          out[(n * NPRED + (t - TOBS)) * 2 + w] = crel;
        }
      }
    } else if (tid < 2) {
      const int d = tid;
      s_scal[d]     = tabs[(n * TOBS + tc) * 2 + d];
      s_scal[2 + d] = trel[(n * TOBS + tc) * 2 + d];
      s_scal[4 + d] = tstep[(n * TOBS + tc) * 2 + d];
    }
    __syncthreads();  // A

    // ---- P1: stage Ax (frozen after t=30), s_xt, s_at ----
    if (t <= TOBS) {
      for (int i = tid; i < KN * EMB; i += 512) {
        const int k = i >> 6, e = i & 63;
        const float s0 = nstep_g[((n * KN + k) * TOBS + tc) * 2 + 0];
        const float s1 = nstep_g[((n * KN + k) * TOBS + tc) * 2 + 1];
        Ax[k][e] = (f16)(s0 * s_wd0[e] + s1 * s_wd1[e] + s_bd[e]);
      }
    }
    if (tid >= 448) {
      const int e = tid - 448;
      s_xt[e] = s_scal[4] * s_wd0[e] + s_scal[5] * s_wd1[e] + s_bd[e];
    }
    if (tid >= 384 && tid < 448) {
      const int a = tid - 384;
      s_at[a] = s_scal[2] * s_wat0[a] + s_scal[3] * s_wat1[a] + s_bat[a];
    }
    __syncthreads();  // B

    // ---- P2: nearby LSTM via MFMA, two e-half passes, double-buffered Ah ----
    if (gate_n) {
      const int nxt = prv ^ 1;
      #pragma unroll
      for (int p = 0; p < 2; ++p) {
        const f16* wb = p ? wb1 : wb0;
        f32x4 acc[3][4];
        #pragma unroll
        for (int rt = 0; rt < 3; ++rt)
          #pragma unroll
          for (int g = 0; g < 4; ++g) acc[rt][g] = (f32x4){0.f, 0.f, 0.f, 0.f};

        #pragma unroll
        for (int kk = 0; kk < 10; ++kk) {
          f16x8 bf[4];
          #pragma unroll
          for (int g = 0; g < 4; ++g)
            bf[g] = *(const f16x8*)(wb + kk * 32768 + g * 512);
          f16x8 af[3];
          #pragma unroll
          for (int rt = 0; rt < 3; ++rt) {
            const int row = rt * 16 + cl;
            const f16* ap = (kk < 2) ? &Ax[row][kk * 32 + koff]
                                     : &Ah[prv][row][(kk - 2) * 32 + koff];
            af[rt] = *(const f16x8*)ap;
          }
          #pragma unroll
          for (int g = 0; g < 4; ++g)
            #pragma unroll
            for (int rt = 0; rt < 3; ++rt)
              acc[rt][g] = __builtin_amdgcn_mfma_f32_16x16x32_f16(af[rt], bf[g], acc[rt][g], 0, 0, 0);
        }

        // activation for this e-half; write new h into Ah[nxt]
        const int e_p = p * 128 + w * 16 + cl;
        #pragma unroll
        for (int rt = 0; rt < 3; ++rt) {
          #pragma unroll
          for (int jj = 0; jj < 4; ++jj) {
            const int row = rt * 16 + kq * 4 + jj;
            const bool nm = is_obs ? (s_nh[row] > (TOBS - t)) : true;
            if (nm) {
              const float iv = acc[rt][0][jj] + bias_q[p][0];
              const float fv = acc[rt][1][jj] + bias_q[p][1];
              const float gv = acc[rt][2][jj] + bias_q[p][2];
              const float ov = acc[rt][3][jj] + bias_q[p][3];
              const float c2 = sigm(fv) * creg[p][rt][jj] + sigm(iv) * tanh_f(gv);
              creg[p][rt][jj] = c2;
              Ah[nxt][row][e_p] = (f16)(sigm(ov) * tanh_f(c2));
            } else {
              Ah[nxt][row][e_p] = Ah[prv][row][e_p];
            }
          }
        }
      }
      prv = nxt;
    }

    // ---- P4: target gate dots (all 512) + attention scores (tid<48, extra work) ----
    const bool tmask = is_obs ? (thist > (TOBS - t)) : true;
    const bool do_t = gate_t && tmask;
    if (do_t) {
      float g = s_bt[tid];
      const f16x8* wp = (const f16x8*)(Wt + tid * 8);
      #pragma unroll
      for (int c8 = 0; c8 < 8; ++c8) {
        const f16x8 wv = wp[c8 * 512];
        #pragma unroll
        for (int j = 0; j < 8; ++j) g += (float)wv[j] * s_xt[c8 * 8 + j];
      }
      #pragma unroll
      for (int c8 = 8; c8 < 24; ++c8) {
        const f16x8 wv = wp[c8 * 512];
        #pragma unroll
        for (int j = 0; j < 8; ++j) g += (float)wv[j] * s_tht[(c8 - 8) * 8 + j];
      }
      s_g[tid] = g;
    }
    if (gate_n && tid < KN) {
      const int k = tid;
      const float a0 = nabs_g[((n * KN + k) * TOBS + tc) * 2 + 0] - s_scal[0];
      const float a1 = nabs_g[((n * KN + k) * TOBS + tc) * 2 + 1] - s_scal[1];
      const bool nm = is_obs ? (s_nh[k] > (TOBS - t)) : true;
      float sc = 0.f;
      for (int a = 0; a < ATTD; ++a)
        sc += (a0 * s_wan0[a] + a1 * s_wan1[a] + s_ban[a]) * s_at[a];
      sc *= currN * 0.125f;
      s_sc[k] = nm ? sc : 0.f;
      s_w[k]  = nm ? 1.f : 0.f;
    }
    __syncthreads();  // E

    // ---- P5: target cell update (tid<128) + softmax (wave 4) ----
    if (do_t && tid < NODE) {
      const float iv = s_g[tid], fv = s_g[NODE + tid];
      const float gv = s_g[2 * NODE + tid], ov = s_g[3 * NODE + tid];
      const float c2 = sigm(fv) * s_tct[tid] + sigm(iv) * tanh_f(gv);
      s_tct[tid] = c2;
      s_tht[tid] = sigm(ov) * tanh_f(c2);
    }
    if (gate_n && w == 4) {
      const bool act = lane < KN;
      const float sc = act ? s_sc[lane] : -1.0e30f;
      const float mf = act ? s_w[lane] : 0.f;
      float mx = sc;
      #pragma unroll
      for (int off = 32; off; off >>= 1) mx = fmaxf(mx, __shfl_xor(mx, off));
      float num = __expf(sc - mx) * mf;
      float sum = num;
      #pragma unroll
      for (int off = 32; off; off >>= 1) sum += __shfl_xor(sum, off);
      if (act) s_w[lane] = num / (sum + 1e-6f);
    }
    __syncthreads();  // F

    // ---- P6: Ht (reads updated Ah[prv]) ----
    if (gate_n && tid < EDGE) {
      float h = 0.f;
      for (int k = 0; k < KN; ++k) h += (float)Ah[prv][k][tid] * s_w[k];
      s_Ht[tid] = h;
    }
    __syncthreads();  // G
  }
}

extern "C" void kernel_launch(void* const* d_in, const int* in_sizes, int n_in,
                              void* d_out, int out_size, void* d_ws, size_t ws_size,
                              hipStream_t stream) {
  const float* img    = (const float*)d_in[0];
  const float* tabs   = (const float*)d_in[1];
  const float* trel   = (const float*)d_in[2];
  const float* tstep  = (const float*)d_in[3];
  const float* nabs   = (const float*)d_in[4];
  const float* nstep  = (const float*)d_in[6];
  const int*   thist  = (const int*)d_in[7];
  const int*   nhist  = (const int*)d_in[8];
  const float* W_disp = (const float*)d_in[9];
  const float* b_disp = (const float*)d_in[10];
  const float* Wih_t  = (const float*)d_in[11];
  const float* Whh_t  = (const float*)d_in[12];
  const float* bih_t  = (const float*)d_in[13];
  const float* bhh_t  = (const float*)d_in[14];
  const float* Wih_n  = (const float*)d_in[15];
  const float* Whh_n  = (const float*)d_in[16];
  const float* bih_n  = (const float*)d_in[17];
  const float* bhh_n  = (const float*)d_in[18];
  const float* W_att_t = (const float*)d_in[19];
  const float* b_att_t = (const float*)d_in[20];
  const float* W_att_n = (const float*)d_in[21];
  const float* b_att_n = (const float*)d_in[22];
  const float* W_pred  = (const float*)d_in[23];
  const float* b_pred  = (const float*)d_in[24];

  char* ws = (char*)d_ws;
  f16*   Wn     = (f16*)(ws);             // 655360 B
  f16*   Wt     = (f16*)(ws + 655360);    // 196608 B
  float* bias_n = (float*)(ws + 851968);  // 4096 B
  float* bias_t = (float*)(ws + 856064);  // 2048 B
  int*   gt_arr = (int*)(ws + 858112);
  int*   gn_arr = (int*)(ws + 858304);
  float* cn_arr = (float*)(ws + 858496);

  prep_kernel<<<64, 256, 0, stream>>>(Wih_n, Whh_n, bih_n, bhh_n, Wih_t, Whh_t,
                                      bih_t, bhh_t, thist, nhist, Wn, Wt,
                                      bias_n, bias_t, gt_arr, gn_arr, cn_arr);
  model_kernel<<<NT, 512, 0, stream>>>(img, tabs, trel, tstep, nabs, nstep,
                                       thist, nhist, W_disp, b_disp,
                                       W_att_t, b_att_t, W_att_n, b_att_n,
                                       W_pred, b_pred,
                                       Wn, Wt, bias_n, bias_t,
                                       gt_arr, gn_arr, cn_arr,
                                       (float*)d_out);
}